// Round 1
// baseline (277.545 us; speedup 1.0000x reference)
//
#include <hip/hip_runtime.h>

// ---------------- GEMM with deg scaling: h[r][c] = dis[r] * sum_k x[r][k]*w[k][c]
// block 256 thr; tile 64 rows x 128 cols; BK=32; each thread 8 rows x 4 cols.
__global__ __launch_bounds__(256)
void gemm_scale_kernel(const float* __restrict__ x, const float* __restrict__ w,
                       const float* __restrict__ dis, float* __restrict__ h, int NL) {
  const int IC = 128, OC = 128, BK = 32;
  __shared__ float xs[64][BK + 4];   // pad to 36 floats: 16B-aligned rows, bank-spread
  __shared__ float ws[BK][OC];
  const int tid = threadIdx.x;
  const int tx = tid & 31;           // cols 4*tx .. 4*tx+3
  const int ty = tid >> 5;           // rows 8*ty .. 8*ty+7
  const int row0 = blockIdx.x * 64;
  float acc[8][4] = {};

  for (int kc = 0; kc < IC; kc += BK) {
    // stage x tile: 64 rows x 32 k  (512 float4, 2 per thread)
#pragma unroll
    for (int i = 0; i < 2; ++i) {
      int idx = i * 256 + tid;
      int r = idx >> 3, c4 = idx & 7;
      float4 v = make_float4(0.f, 0.f, 0.f, 0.f);
      int gr = row0 + r;
      if (gr < NL) v = *(const float4*)&x[(size_t)gr * IC + kc + c4 * 4];
      *(float4*)&xs[r][c4 * 4] = v;
    }
    // stage w tile: 32 k x 128 cols (1024 float4, 4 per thread)
#pragma unroll
    for (int i = 0; i < 4; ++i) {
      int idx = i * 256 + tid;
      int r = idx >> 5, c4 = idx & 31;
      *(float4*)&ws[r][c4 * 4] = *(const float4*)&w[(size_t)(kc + r) * OC + c4 * 4];
    }
    __syncthreads();
#pragma unroll
    for (int k = 0; k < BK; ++k) {
      float4 wv = *(const float4*)&ws[k][tx * 4];
#pragma unroll
      for (int i = 0; i < 8; ++i) {
        float xv = xs[ty * 8 + i][k];
        acc[i][0] += xv * wv.x;
        acc[i][1] += xv * wv.y;
        acc[i][2] += xv * wv.z;
        acc[i][3] += xv * wv.w;
      }
    }
    __syncthreads();
  }
#pragma unroll
  for (int i = 0; i < 8; ++i) {
    int r = row0 + ty * 8 + i;
    if (r < NL) {
      float d = dis[r];
      float4 o;
      o.x = acc[i][0] * d; o.y = acc[i][1] * d;
      o.z = acc[i][2] * d; o.w = acc[i][3] * d;
      *(float4*)&h[(size_t)r * OC + tx * 4] = o;
    }
  }
}

// ---------------- histogram of dst (< num_owned only)
__global__ void hist_kernel(const int* __restrict__ row, int* __restrict__ counts,
                            int NE, int num_owned) {
  int i = blockIdx.x * blockDim.x + threadIdx.x;
  int stride = gridDim.x * blockDim.x;
  for (; i < NE; i += stride) {
    int r = row[i];
    if (r < num_owned) atomicAdd(&counts[r], 1);
  }
}

// ---------------- 2-level exclusive scan
__global__ __launch_bounds__(256)
void scan_block_kernel(const int* __restrict__ counts, int* __restrict__ offsets,
                       int* __restrict__ bsum, int n) {
  __shared__ int lds[256];
  int tid = threadIdx.x;
  int i = blockIdx.x * 256 + tid;
  int v = (i < n) ? counts[i] : 0;
  lds[tid] = v;
  __syncthreads();
#pragma unroll
  for (int off = 1; off < 256; off <<= 1) {
    int t = (tid >= off) ? lds[tid - off] : 0;
    __syncthreads();
    lds[tid] += t;
    __syncthreads();
  }
  if (i < n) offsets[i] = lds[tid] - v;   // exclusive within block
  if (tid == 255) bsum[blockIdx.x] = lds[255];
}

__global__ __launch_bounds__(512)
void scan_top_kernel(const int* __restrict__ bsum, int* __restrict__ bsum2, int nb) {
  __shared__ int lds[512];
  int tid = threadIdx.x;
  int v = (tid < nb) ? bsum[tid] : 0;
  lds[tid] = v;
  __syncthreads();
  for (int off = 1; off < 512; off <<= 1) {
    int t = (tid >= off) ? lds[tid - off] : 0;
    __syncthreads();
    lds[tid] += t;
    __syncthreads();
  }
  if (tid < nb) bsum2[tid] = lds[tid] - v;  // exclusive block offsets
}

__global__ void add_off_kernel(int* __restrict__ offsets, const int* __restrict__ bsum2, int n) {
  int i = blockIdx.x * 256 + threadIdx.x;
  if (i < n) offsets[i] += bsum2[blockIdx.x];
}

// ---------------- CSR fill
__global__ void fill_kernel(const int* __restrict__ row, const int* __restrict__ col,
                            const int* __restrict__ offsets, int* __restrict__ cursor,
                            int* __restrict__ csr_col, int NE, int num_owned) {
  int i = blockIdx.x * blockDim.x + threadIdx.x;
  int stride = gridDim.x * blockDim.x;
  for (; i < NE; i += stride) {
    int r = row[i];
    if (r < num_owned) {
      int p = atomicAdd(&cursor[r], 1);
      csr_col[offsets[r] + p] = col[i];
    }
  }
}

// ---------------- gather-sum aggregate: one wave per owned node, lane owns 2 cols
__global__ __launch_bounds__(256)
void agg_kernel(const float* __restrict__ h, const int* __restrict__ csr_col,
                const int* __restrict__ offsets, const int* __restrict__ counts,
                const float* __restrict__ dis, const float* __restrict__ bias,
                float* __restrict__ out, int num_owned) {
  int node = blockIdx.x * 4 + (threadIdx.x >> 6);
  int lane = threadIdx.x & 63;
  if (node >= num_owned) return;
  int start = offsets[node];
  int cnt = counts[node];
  int c0 = lane * 2;
  float ax = 0.f, ay = 0.f;
  int e = 0;
  for (; e + 4 <= cnt; e += 4) {
    int s0 = csr_col[start + e + 0];
    int s1 = csr_col[start + e + 1];
    int s2 = csr_col[start + e + 2];
    int s3 = csr_col[start + e + 3];
    float2 v0 = *(const float2*)&h[(size_t)s0 * 128 + c0];
    float2 v1 = *(const float2*)&h[(size_t)s1 * 128 + c0];
    float2 v2 = *(const float2*)&h[(size_t)s2 * 128 + c0];
    float2 v3 = *(const float2*)&h[(size_t)s3 * 128 + c0];
    ax += v0.x + v1.x + v2.x + v3.x;
    ay += v0.y + v1.y + v2.y + v3.y;
  }
  for (; e < cnt; ++e) {
    int s = csr_col[start + e];
    float2 v = *(const float2*)&h[(size_t)s * 128 + c0];
    ax += v.x; ay += v.y;
  }
  float d = dis[node];
  float2 b = *(const float2*)&bias[c0];
  float2 o;
  o.x = ax * d + b.x;
  o.y = ay * d + b.y;
  *(float2*)&out[(size_t)node * 128 + c0] = o;
}

extern "C" void kernel_launch(void* const* d_in, const int* in_sizes, int n_in,
                              void* d_out, int out_size, void* d_ws, size_t ws_size,
                              hipStream_t stream) {
  const float* x    = (const float*)d_in[0];
  const float* w    = (const float*)d_in[1];
  const float* bias = (const float*)d_in[2];
  const float* dis  = (const float*)d_in[3];
  const int*   row  = (const int*)d_in[4];
  const int*   col  = (const int*)d_in[5];

  const int OC = in_sizes[2];            // 128
  const int IC = in_sizes[1] / OC;       // 128
  const int NL = in_sizes[0] / IC;       // 100000
  const int NE = in_sizes[4];            // 1600000
  const int num_owned = out_size / OC;   // 80000
  float* out = (float*)d_out;

  // carve workspace (~59 MB total)
  char* ws = (char*)d_ws;
  size_t off = 0;
  auto alloc = [&](size_t bytes) -> void* {
    void* p = ws + off;
    off += (bytes + 255) & ~(size_t)255;
    return p;
  };
  float* h      = (float*)alloc((size_t)NL * OC * sizeof(float));
  int*   counts = (int*)alloc((size_t)num_owned * sizeof(int));
  int*   offs   = (int*)alloc((size_t)num_owned * sizeof(int));
  int*   cursor = (int*)alloc((size_t)num_owned * sizeof(int));
  int*   bsum   = (int*)alloc(4096);
  int*   bsum2  = (int*)alloc(4096);
  int*   csr    = (int*)alloc((size_t)NE * sizeof(int));
  (void)ws_size; (void)n_in;

  hipMemsetAsync(counts, 0, (size_t)num_owned * sizeof(int), stream);
  hipMemsetAsync(cursor, 0, (size_t)num_owned * sizeof(int), stream);

  gemm_scale_kernel<<<(NL + 63) / 64, 256, 0, stream>>>(x, w, dis, h, NL);
  hist_kernel<<<1024, 256, 0, stream>>>(row, counts, NE, num_owned);

  int nb = (num_owned + 255) / 256;      // 313 <= 512
  scan_block_kernel<<<nb, 256, 0, stream>>>(counts, offs, bsum, num_owned);
  scan_top_kernel<<<1, 512, 0, stream>>>(bsum, bsum2, nb);
  add_off_kernel<<<nb, 256, 0, stream>>>(offs, bsum2, num_owned);

  fill_kernel<<<1024, 256, 0, stream>>>(row, col, offs, cursor, csr, NE, num_owned);
  agg_kernel<<<(num_owned + 3) / 4, 256, 0, stream>>>(h, csr, offs, counts, dis, bias, out, num_owned);
}

// Round 4
// 249.943 us; speedup vs baseline: 1.1104x; 1.1104x over previous
//
#include <hip/hip_runtime.h>

typedef unsigned int uint32;

__device__ __forceinline__ unsigned short f2bf(float f) {
  uint32 b = __float_as_uint(f);
  uint32 r = (b + 0x7fffu + ((b >> 16) & 1u)) >> 16;   // round-to-nearest-even
  return (unsigned short)r;
}
__device__ __forceinline__ float bf2f(unsigned short u) {
  return __uint_as_float(((uint32)u) << 16);
}

// ---------------- zero int buffer (compute-engine; replaces hipMemsetAsync)
__global__ __launch_bounds__(256)
void zero_kernel(int* __restrict__ p, int n) {
  int i = blockIdx.x * 256 + threadIdx.x;
  if (i < n) p[i] = 0;
}

// ---------------- GEMM with deg scaling: h[r][c] = dis[r] * sum_k x[r][k]*w[k][c]
// h stored bf16. block 256; tile 64 rows x 128 cols; BK=32; thread: 8 rows x 4 cols.
__global__ __launch_bounds__(256)
void gemm_scale_kernel(const float* __restrict__ x, const float* __restrict__ w,
                       const float* __restrict__ dis, unsigned short* __restrict__ hb, int NL) {
  const int IC = 128, OC = 128, BK = 32;
  __shared__ float xs[64][BK + 4];
  __shared__ float ws[BK][OC];
  const int tid = threadIdx.x;
  const int tx = tid & 31;
  const int ty = tid >> 5;
  const int row0 = blockIdx.x * 64;
  float acc[8][4] = {};

  for (int kc = 0; kc < IC; kc += BK) {
#pragma unroll
    for (int i = 0; i < 2; ++i) {
      int idx = i * 256 + tid;
      int r = idx >> 3, c4 = idx & 7;
      float4 v = make_float4(0.f, 0.f, 0.f, 0.f);
      int gr = row0 + r;
      if (gr < NL) v = *(const float4*)&x[(size_t)gr * IC + kc + c4 * 4];
      *(float4*)&xs[r][c4 * 4] = v;
    }
#pragma unroll
    for (int i = 0; i < 4; ++i) {
      int idx = i * 256 + tid;
      int r = idx >> 5, c4 = idx & 31;
      *(float4*)&ws[r][c4 * 4] = *(const float4*)&w[(size_t)(kc + r) * OC + c4 * 4];
    }
    __syncthreads();
#pragma unroll
    for (int k = 0; k < BK; ++k) {
      float4 wv = *(const float4*)&ws[k][tx * 4];
#pragma unroll
      for (int i = 0; i < 8; ++i) {
        float xv = xs[ty * 8 + i][k];
        acc[i][0] += xv * wv.x;
        acc[i][1] += xv * wv.y;
        acc[i][2] += xv * wv.z;
        acc[i][3] += xv * wv.w;
      }
    }
    __syncthreads();
  }
#pragma unroll
  for (int i = 0; i < 8; ++i) {
    int r = row0 + ty * 8 + i;
    if (r < NL) {
      float d = dis[r];
      ushort4 o;
      o.x = f2bf(acc[i][0] * d);
      o.y = f2bf(acc[i][1] * d);
      o.z = f2bf(acc[i][2] * d);
      o.w = f2bf(acc[i][3] * d);
      *(ushort4*)&hb[(size_t)r * OC + tx * 4] = o;
    }
  }
}

// ---------------- histogram of dst (< num_owned only)
__global__ void hist_kernel(const int* __restrict__ row, int* __restrict__ counts,
                            int NE, int num_owned) {
  int i = blockIdx.x * blockDim.x + threadIdx.x;
  int stride = gridDim.x * blockDim.x;
  for (; i < NE; i += stride) {
    int r = row[i];
    if (r < num_owned) atomicAdd(&counts[r], 1);
  }
}

// ---------------- 2-level exclusive scan
__global__ __launch_bounds__(256)
void scan_block_kernel(const int* __restrict__ counts, int* __restrict__ offsets,
                       int* __restrict__ bsum, int n) {
  __shared__ int lds[256];
  int tid = threadIdx.x;
  int i = blockIdx.x * 256 + tid;
  int v = (i < n) ? counts[i] : 0;
  lds[tid] = v;
  __syncthreads();
#pragma unroll
  for (int off = 1; off < 256; off <<= 1) {
    int t = (tid >= off) ? lds[tid - off] : 0;
    __syncthreads();
    lds[tid] += t;
    __syncthreads();
  }
  if (i < n) offsets[i] = lds[tid] - v;
  if (tid == 255) bsum[blockIdx.x] = lds[255];
}

__global__ __launch_bounds__(512)
void scan_top_kernel(const int* __restrict__ bsum, int* __restrict__ bsum2, int nb) {
  __shared__ int lds[512];
  int tid = threadIdx.x;
  int v = (tid < nb) ? bsum[tid] : 0;
  lds[tid] = v;
  __syncthreads();
  for (int off = 1; off < 512; off <<= 1) {
    int t = (tid >= off) ? lds[tid - off] : 0;
    __syncthreads();
    lds[tid] += t;
    __syncthreads();
  }
  if (tid < nb) bsum2[tid] = lds[tid] - v;
}

// add global block offset; also produce end[] = start + count for agg
__global__ void add_off_kernel(int* __restrict__ offsets, int* __restrict__ endb,
                               const int* __restrict__ bsum2, const int* __restrict__ counts,
                               int n) {
  int i = blockIdx.x * 256 + threadIdx.x;
  if (i < n) {
    int o = offsets[i] + bsum2[blockIdx.x];
    offsets[i] = o;
    endb[i] = o + counts[i];
  }
}

// ---------------- CSR fill
__global__ void fill_kernel(const int* __restrict__ row, const int* __restrict__ col,
                            const int* __restrict__ offsets, int* __restrict__ cursor,
                            int* __restrict__ csr_col, int NE, int num_owned) {
  int i = blockIdx.x * blockDim.x + threadIdx.x;
  int stride = gridDim.x * blockDim.x;
  for (; i < NE; i += stride) {
    int r = row[i];
    if (r < num_owned) {
      int p = atomicAdd(&cursor[r], 1);
      csr_col[offsets[r] + p] = col[i];
    }
  }
}

// ---------------- gather-sum aggregate: one wave per owned node, lane owns 2 bf16 cols
__global__ __launch_bounds__(256)
void agg_kernel(const unsigned short* __restrict__ hb, const int* __restrict__ csr_col,
                const int* __restrict__ offsets, const int* __restrict__ endb,
                const float* __restrict__ dis, const float* __restrict__ bias,
                float* __restrict__ out, int num_owned) {
  int node = blockIdx.x * 4 + (threadIdx.x >> 6);
  int lane = threadIdx.x & 63;
  if (node >= num_owned) return;
  int e = offsets[node];
  int endv = endb[node];
  int c0 = lane * 2;
  float ax = 0.f, ay = 0.f;
  for (; e + 8 <= endv; e += 8) {
    int s[8];
#pragma unroll
    for (int j = 0; j < 8; ++j) s[j] = csr_col[e + j];
    uint32 v[8];
#pragma unroll
    for (int j = 0; j < 8; ++j) v[j] = *(const uint32*)&hb[(size_t)s[j] * 128 + c0];
#pragma unroll
    for (int j = 0; j < 8; ++j) {
      ax += bf2f((unsigned short)(v[j] & 0xffff));
      ay += bf2f((unsigned short)(v[j] >> 16));
    }
  }
  for (; e < endv; ++e) {
    int s = csr_col[e];
    uint32 v = *(const uint32*)&hb[(size_t)s * 128 + c0];
    ax += bf2f((unsigned short)(v & 0xffff));
    ay += bf2f((unsigned short)(v >> 16));
  }
  float d = dis[node];
  float2 b = *(const float2*)&bias[c0];
  float2 o;
  o.x = ax * d + b.x;
  o.y = ay * d + b.y;
  *(float2*)&out[(size_t)node * 128 + c0] = o;
}

extern "C" void kernel_launch(void* const* d_in, const int* in_sizes, int n_in,
                              void* d_out, int out_size, void* d_ws, size_t ws_size,
                              hipStream_t stream) {
  const float* x    = (const float*)d_in[0];
  const float* w    = (const float*)d_in[1];
  const float* bias = (const float*)d_in[2];
  const float* dis  = (const float*)d_in[3];
  const int*   row  = (const int*)d_in[4];
  const int*   col  = (const int*)d_in[5];

  const int OC = in_sizes[2];            // 128
  const int IC = in_sizes[1] / OC;       // 128
  const int NL = in_sizes[0] / IC;       // 100000
  const int NE = in_sizes[4];            // 1600000
  const int num_owned = out_size / OC;   // 80000
  float* out = (float*)d_out;

  char* ws = (char*)d_ws;
  size_t off = 0;
  auto alloc = [&](size_t bytes) -> void* {
    void* p = ws + off;
    off += (bytes + 255) & ~(size_t)255;
    return p;
  };
  unsigned short* hb = (unsigned short*)alloc((size_t)NL * OC * sizeof(unsigned short));
  int* cnt_cur = (int*)alloc((size_t)2 * num_owned * sizeof(int));  // counts | cursor (contiguous)
  int* counts  = cnt_cur;
  int* cursor  = cnt_cur + num_owned;
  int* offs    = (int*)alloc((size_t)num_owned * sizeof(int));
  int* endb    = (int*)alloc((size_t)num_owned * sizeof(int));
  int* bsum    = (int*)alloc(4096);
  int* bsum2   = (int*)alloc(4096);
  int* csr     = (int*)alloc((size_t)NE * sizeof(int));
  (void)ws_size; (void)n_in;

  // all nodes on the compute engine, single stream -> strictly ordered graph
  zero_kernel<<<(2 * num_owned + 255) / 256, 256, 0, stream>>>(cnt_cur, 2 * num_owned);
  gemm_scale_kernel<<<(NL + 63) / 64, 256, 0, stream>>>(x, w, dis, hb, NL);
  hist_kernel<<<1024, 256, 0, stream>>>(row, counts, NE, num_owned);

  int nb = (num_owned + 255) / 256;      // 313 <= 512
  scan_block_kernel<<<nb, 256, 0, stream>>>(counts, offs, bsum, num_owned);
  scan_top_kernel<<<1, 512, 0, stream>>>(bsum, bsum2, nb);
  add_off_kernel<<<nb, 256, 0, stream>>>(offs, endb, bsum2, counts, num_owned);

  fill_kernel<<<1024, 256, 0, stream>>>(row, col, offs, cursor, csr, NE, num_owned);
  agg_kernel<<<(num_owned + 3) / 4, 256, 0, stream>>>(hb, csr, offs, endb, dis, bias, out, num_owned);
}